// Round 12
// baseline (195.335 us; speedup 1.0000x reference)
//
#include <hip/hip_runtime.h>
#include <math.h>

// Problem constants
constexpr int kB    = 64;
constexpr int kN    = 32;
constexpr int kDIN  = 128;
constexpr int kH    = 256;
constexpr int kG4   = 1024;   // 4*H
constexpr int kDOUT = 128;
constexpr int kBN   = 2048;   // B*N

typedef __attribute__((ext_vector_type(8))) short bf16x8;
typedef __attribute__((ext_vector_type(4))) float f32x4;

// fast sigmoid/tanh: v_exp_f32 + v_rcp_f32 (1-2 ulp, far below bf16-h noise)
__device__ __forceinline__ float sigm(float x) {
    return __builtin_amdgcn_rcpf(1.0f + __expf(-x));
}
__device__ __forceinline__ float tanh_f(float x) {
    return 1.0f - 2.0f * __builtin_amdgcn_rcpf(1.0f + __expf(2.0f * x));
}

// fp32 -> bf16 bits, round-to-nearest-even
__device__ __forceinline__ short f2bf(float f) {
    union { float f; unsigned u; } v; v.f = f;
    unsigned r = v.u + 0x7fffu + ((v.u >> 16) & 1u);
    return (short)(r >> 16);
}
__device__ __forceinline__ float bf2f(short h) {
    union { unsigned u; float f; } v; v.u = ((unsigned)(unsigned short)h) << 16;
    return v.f;
}
// fp32 -> (hi, lo) bf16 pair: hi + lo ~ f with ~2^-17 relative error
__device__ __forceinline__ void split_bf(float f, short& hi, short& lo) {
    const short h = f2bf(f);
    hi = h;
    lo = f2bf(f - bf2f(h));
}
// two f32x4 -> hi/lo bf16x8 fragments
__device__ __forceinline__ void cvt8(const f32x4 a, const f32x4 b,
                                     bf16x8& hi, bf16x8& lo) {
    #pragma unroll
    for (int j = 0; j < 4; ++j) { short h, l; split_bf(a[j], h, l); hi[j] = h; lo[j] = l; }
    #pragma unroll
    for (int j = 0; j < 4; ++j) { short h, l; split_bf(b[j], h, l); hi[4 + j] = h; lo[4 + j] = l; }
}

// ---------------------------------------------------------------------------
// prep (128 blocks x 256 thr): ONLY the pack k1 depends on -- W_ih hi/lo
// fragment-contiguous.
// ---------------------------------------------------------------------------
__global__ __launch_bounds__(256) void prep_k(
    const float* __restrict__ Wihf, const float* __restrict__ Wihr,
    short* __restrict__ Wihh_f, short* __restrict__ Wihl_f,
    short* __restrict__ Wihh_r, short* __restrict__ Wihl_r)
{
    const int bx  = blockIdx.x;
    const int tid = threadIdx.x;
    const int dir = bx >> 6;
    const int ng  = bx & 63;
    const float* src = dir ? Wihr : Wihf;
    short* dh = (dir ? Wihh_r : Wihh_f);
    short* dl = (dir ? Wihl_r : Wihl_f);
    const int kt   = tid >> 6;
    const int lane = tid & 63;
    const int qd   = lane >> 4, l = lane & 15;
    const int ks   = kt * 32 + qd * 8;
    bf16x8 vh, vl;
    #pragma unroll
    for (int j = 0; j < 8; ++j) {
        short h, lo;
        split_bf(src[(size_t)(ng * 16 + l) * kDIN + ks + j], h, lo);
        vh[j] = h; vl[j] = lo;
    }
    const size_t off = (size_t)((ng * 4 + kt) * 64 + lane) * 8;
    *(bf16x8*)(dh + off) = vh;
    *(bf16x8*)(dl + off) = vl;
}

// ---------------------------------------------------------------------------
// k1_front (400 blocks x 256 thr), fused GEMM + packs (unchanged from r10).
// ---------------------------------------------------------------------------
__global__ __launch_bounds__(256)
__attribute__((amdgpu_waves_per_eu(2, 2))) void k1_front(
    const float* __restrict__ x,
    const short* __restrict__ Wihh_f, const short* __restrict__ Wihl_f,
    const short* __restrict__ Wihh_r, const short* __restrict__ Wihl_r,
    const float* __restrict__ Whhf, const float* __restrict__ Whhr,
    const float* __restrict__ Wfc,  const float* __restrict__ mask,
    float* __restrict__ xWP_f, float* __restrict__ xWP_r,
    short* __restrict__ Wp_f,  short* __restrict__ Wp_r,
    short* __restrict__ Wfch,  short* __restrict__ Wfcl,
    float* __restrict__ mask_t)
{
    __shared__ float xs[64][128];               // 32 KB (GEMM blocks only)
    const int bx  = blockIdx.x;
    const int tid = threadIdx.x;

    if (bx >= 392) {                       // mask transpose
        const int base = (bx - 392) * 8192 + tid;
        #pragma unroll
        for (int i = 0; i < 32; ++i) {
            const int idx = base + i * 256;
            const int n = idx >> 11, tt = (idx >> 6) & 31, b = idx & 63;
            mask_t[idx] = mask[(size_t)b * 1024 + n * 32 + tt];
        }
        return;
    }
    if (bx >= 384) {                       // W_fc hi/lo pack
        const int ng   = bx - 384;         // 0..7
        const int lane = tid & 63;
        const int qd   = lane >> 4, l = lane & 15;
        #pragma unroll
        for (int p = 0; p < 4; ++p) {
            const int kt = p * 4 + (tid >> 6);
            const int ks = kt * 32 + qd * 8;
            bf16x8 vh, vl;
            #pragma unroll
            for (int j = 0; j < 8; ++j) {
                short h, lo;
                split_bf(Wfc[(size_t)(ng * 16 + l) * (2 * kH) + ks + j], h, lo);
                vh[j] = h; vl[j] = lo;
            }
            const size_t off = (size_t)((ng * 16 + kt) * 64 + lane) * 8;
            *(bf16x8*)(Wfch + off) = vh;
            *(bf16x8*)(Wfcl + off) = vl;
        }
        return;
    }
    if (bx >= 256) {                       // W_hh fragment pack (bf16, k2)
        const int idx = bx - 256;
        const int dir = idx >> 6;
        const int wv  = (idx >> 3) & 7;
        const int kt  = idx & 7;
        const float* src = dir ? Whhr : Whhf;
        short* dst = (dir ? Wp_r : Wp_f) + (size_t)((wv * 8 + kt) * 8) * 512;
        for (int i = tid; i < 512; i += 256) {
            const int tau = i >> 6, lane = i & 63;
            const int qd = lane >> 4, l = lane & 15;
            const int gate = (tau >> 1) * 256 + wv * 32 + (tau & 1) * 16 + l;
            const int ks = kt * 32 + qd * 8;
            bf16x8 v;
            #pragma unroll
            for (int j = 0; j < 8; ++j) v[j] = f2bf(src[(size_t)gate * kH + ks + j]);
            *(bf16x8*)(dst + tau * 512 + lane * 8) = v;
        }
        return;
    }

    // ---- xW GEMM blocks ----
    const int w    = tid >> 6;                  // wave 0..3
    const int lane = tid & 63;
    const int quad = lane >> 4;
    const int l15  = lane & 15;

    const int dir  = bx >> 7;
    const int rest = bx & 127;
    const int t    = rest >> 2;
    const int nt   = rest & 3;                  // 256-gate tile

    const short* __restrict__ Wh = dir ? Wihh_r : Wihh_f;
    const short* __restrict__ Wl = dir ? Wihl_r : Wihl_f;
    float* __restrict__ xWP = dir ? xWP_r : xWP_f;

    #pragma unroll
    for (int p = 0; p < 8; ++p) {
        const int idx = p * 256 + tid;
        const int row = idx >> 5, c4 = idx & 31;
        *(f32x4*)&xs[row][c4 * 4] =
            *(const f32x4*)&x[((size_t)row * 32 + t) * kDIN + c4 * 4];
    }
    __syncthreads();

    f32x4 acc[4][4];                            // [tau][Mt]
    #pragma unroll
    for (int tau = 0; tau < 4; ++tau)
        #pragma unroll
        for (int Mt = 0; Mt < 4; ++Mt) acc[tau][Mt] = (f32x4){0.f, 0.f, 0.f, 0.f};

    #pragma unroll
    for (int kt = 0; kt < 4; ++kt) {
        bf16x8 ah[4], al[4];                    // per-kt A cvt: low residency
        #pragma unroll
        for (int Mt = 0; Mt < 4; ++Mt) {
            const f32x4 a0 = *(const f32x4*)&xs[Mt * 16 + l15][kt * 32 + quad * 8];
            const f32x4 a1 = *(const f32x4*)&xs[Mt * 16 + l15][kt * 32 + quad * 8 + 4];
            cvt8(a0, a1, ah[Mt], al[Mt]);
        }
        bf16x8 bh[4], bl[4];
        #pragma unroll
        for (int tau = 0; tau < 4; ++tau) {
            const int g16 = nt * 16 + w * 4 + tau;
            const size_t off = (size_t)((g16 * 4 + kt) * 64 + lane) * 8;
            bh[tau] = *(const bf16x8*)(Wh + off);
            bl[tau] = *(const bf16x8*)(Wl + off);
        }
        #pragma unroll
        for (int tau = 0; tau < 4; ++tau)
            #pragma unroll
            for (int Mt = 0; Mt < 4; ++Mt) {
                acc[tau][Mt] = __builtin_amdgcn_mfma_f32_16x16x32_bf16(
                    ah[Mt], bh[tau], acc[tau][Mt], 0, 0, 0);
                acc[tau][Mt] = __builtin_amdgcn_mfma_f32_16x16x32_bf16(
                    ah[Mt], bl[tau], acc[tau][Mt], 0, 0, 0);
                acc[tau][Mt] = __builtin_amdgcn_mfma_f32_16x16x32_bf16(
                    al[Mt], bh[tau], acc[tau][Mt], 0, 0, 0);
            }
    }

    #pragma unroll
    for (int tau = 0; tau < 4; ++tau) {
        const int g16  = nt * 16 + w * 4 + tau;
        const int wg   = (g16 >> 1) & 7;
        const int taug = (g16 >> 4) * 2 + (g16 & 1);
        #pragma unroll
        for (int Mt = 0; Mt < 4; ++Mt)
            ((f32x4*)xWP)[(size_t)(t * 4 + Mt) * 4096 + wg * 512 + taug * 64
                          + quad * 16 + l15] = acc[tau][Mt];
    }
}

// ---------------------------------------------------------------------------
// k2: bidirectional LSTM recurrence, bf16 MFMA fp32 accumulate.
// ROUND-12: 512 thr = 8 waves at waves_per_eu(2,2) -> 256-reg budget,
// with the 4-2-2 tier split (NOT r8's 5-2-1 which spilled at ~260 live regs):
//   kt 0..3: registers  wreg[4][8] = 128 regs
//   kt 4..5: LDS stash  (128 KB, wave-private)
//   kt 6..7: streamed from L2 (128 KB/step)
// Live set ~227 of 256 -> ~30 regs headroom so the compiler can FINALLY
// pipeline the tier-3 loads + xW prefetch under the kt0-5 MFMA/LDS phase
// (the 16-wave config was budget-locked at exactly 128: zero headroom, all
// loads issued late and consumed immediately -> sum-of-pipes per step).
// h-LDS re-read traffic also halves (8 waves x 8 KB). Wave w owns units
// w*32..+31, all 4 gates (tau = g*2+q). Raw barrier (r11, validated) kept.
// ---------------------------------------------------------------------------
__global__ __launch_bounds__(512)
__attribute__((amdgpu_waves_per_eu(2, 2))) void k2_lstm(
    const float* __restrict__ mask_t,
    const float* __restrict__ xWP_f, const float* __restrict__ xWP_r,
    const short* __restrict__ Wp_f, const short* __restrict__ Wp_r,
    const float* __restrict__ b_f,  const float* __restrict__ b_r,
    float* __restrict__ y)
{
    constexpr int HP = 272;
    __shared__ short h_lds[2][16][HP];          // 17408 B
    __shared__ short w_lds[8][16][512];         // 131072 B: kt=4,5 x 8tau per wave

    const int tid  = threadIdx.x;
    const int w    = tid >> 6;                  // 0..7
    const int lane = tid & 63;
    const int quad = lane >> 4;
    const int l15  = lane & 15;

    const int bx    = blockIdx.x;
    const int dir   = bx >> 7;                  // 0 fwd, 1 rev
    const int rest  = bx & 127;
    const int n_seq = rest >> 2;                // 0..31
    const int bq    = rest & 3;                 // batch quarter (16 each)

    const float* __restrict__ xWP = dir ? xWP_r : xWP_f;
    const short* __restrict__ Wp  = dir ? Wp_r  : Wp_f;
    const float* __restrict__ bb  = dir ? b_r   : b_f;

    // tau = g*2 + q; wave w == packed wv
    float bias[8];
    #pragma unroll
    for (int g = 0; g < 4; ++g)
        #pragma unroll
        for (int q = 0; q < 2; ++q)
            bias[g * 2 + q] = bb[g * 256 + w * 32 + q * 16 + l15];

    // tier 1: kt 0..3 persisted in registers (128 regs)
    bf16x8 wreg[4][8];
    #pragma unroll
    for (int kt = 0; kt < 4; ++kt)
        #pragma unroll
        for (int tau = 0; tau < 8; ++tau)
            wreg[kt][tau] = *(const bf16x8*)(
                Wp + (size_t)((w * 8 + kt) * 8 + tau) * 512 + lane * 8);

    // tier 2: kt 4..5 in this wave's private LDS stash
    #pragma unroll
    for (int f = 0; f < 16; ++f) {
        const int kt = 4 + (f >> 3), tau = f & 7;
        *(bf16x8*)&w_lds[w][f][lane * 8] = *(const bf16x8*)(
            Wp + (size_t)((w * 8 + kt) * 8 + tau) * 512 + lane * 8);
    }

    float c[8];
    #pragma unroll
    for (int i = 0; i < 8; ++i) c[i] = 0.f;

    const int nsteps = dir ? (kN - n_seq) : (n_seq + 1);
    const int t0     = dir ? (kN - 1) : 0;

    // per-wave xW base (f32x4 units): (t*4+bq)*4096 + w*512 + tau*64 + lane
    const f32x4* xWPv = (const f32x4*)xWP + (w * 512 + lane);

    // initial prefetch of packed xW + mask for t0
    f32x4 xwn[8];
    f32x4 mkn;
    {
        const f32x4* xb4 = xWPv + (size_t)(t0 * 4 + bq) * 4096;
        #pragma unroll
        for (int tau = 0; tau < 8; ++tau) xwn[tau] = xb4[tau * 64];
        mkn = ((const f32x4*)mask_t)[(n_seq * 32 + t0) * 16 + bq * 4 + quad];
    }

    int zro = 0;                  // opaque 0: blocks LICM of tier-3 loads

    int cur = 0;
    for (int it = 0; it < nsteps; ++it) {
        const int t = dir ? (kN - 1 - it) : it;

        asm volatile("" : "+v"(zro));   // redefine each step -> loop-variant

        // consume prefetched xW/mask into acc
        f32x4 acc[8];
        #pragma unroll
        for (int tau = 0; tau < 8; ++tau)
            #pragma unroll
            for (int r = 0; r < 4; ++r)
                acc[tau][r] = fmaf(mkn[r], xwn[tau][r], bias[tau]);

        // prefetch next step's xW/mask (overlaps K-loop + epilogue + barrier)
        {
            const int tn = (it + 1 < nsteps) ? (dir ? t - 1 : t + 1) : t;
            const f32x4* xb4 = xWPv + (size_t)(tn * 4 + bq) * 4096;
            #pragma unroll
            for (int tau = 0; tau < 8; ++tau) xwn[tau] = xb4[tau * 64];
            mkn = ((const f32x4*)mask_t)[(n_seq * 32 + tn) * 16 + bq * 4 + quad];
        }

        // K loop: kt 0..3 regs, kt 4..5 LDS stash, kt 6..7 streamed from L2
        if (it > 0) {
            #pragma unroll
            for (int kt = 0; kt < 4; ++kt) {
                const bf16x8 a = *(const bf16x8*)&h_lds[cur][l15][kt * 32 + quad * 8];
                #pragma unroll
                for (int tau = 0; tau < 8; ++tau)
                    acc[tau] = __builtin_amdgcn_mfma_f32_16x16x32_bf16(
                        a, wreg[kt][tau], acc[tau], 0, 0, 0);
            }
            #pragma unroll
            for (int kk = 0; kk < 2; ++kk) {
                const int kt = 4 + kk;
                const bf16x8 a = *(const bf16x8*)&h_lds[cur][l15][kt * 32 + quad * 8];
                #pragma unroll
                for (int tau = 0; tau < 8; ++tau) {
                    const bf16x8 wf = *(const bf16x8*)&w_lds[w][kk * 8 + tau][lane * 8];
                    acc[tau] = __builtin_amdgcn_mfma_f32_16x16x32_bf16(
                        a, wf, acc[tau], 0, 0, 0);
                }
            }
            #pragma unroll
            for (int kk = 0; kk < 2; ++kk) {
                const int kt = 6 + kk;
                const bf16x8 a = *(const bf16x8*)&h_lds[cur][l15][kt * 32 + quad * 8];
                #pragma unroll
                for (int tau = 0; tau < 8; ++tau) {
                    const bf16x8 wf = *(const bf16x8*)(
                        Wp + (size_t)((w * 8 + kt) * 8 + tau) * 512
                           + lane * 8 + zro);
                    acc[tau] = __builtin_amdgcn_mfma_f32_16x16x32_bf16(
                        a, wf, acc[tau], 0, 0, 0);
                }
            }
        }

        // epilogue: lane owns units u = w*32+q*16+l15, rows m = quad*4+r
        const int nxt = cur ^ 1;
        #pragma unroll
        for (int q = 0; q < 2; ++q)
            #pragma unroll
            for (int r = 0; r < 4; ++r) {
                const int ci = q * 4 + r;
                const float gI = acc[0 + q][r];
                const float gF = acc[2 + q][r];
                const float gG = acc[4 + q][r];
                const float gO = acc[6 + q][r];
                const float ct = sigm(gF) * c[ci] + sigm(gI) * tanh_f(gG);
                c[ci] = ct;
                const float hn = sigm(gO) * tanh_f(ct);
                const int m = quad * 4 + r;
                const int u = w * 32 + q * 16 + l15;
                h_lds[nxt][m][u] = f2bf(hn);
                if (it == nsteps - 1)
                    y[((size_t)(bq * 16 + m) * kN + n_seq) * (2 * kH)
                      + dir * kH + u] = hn;
            }
        if (it + 1 < nsteps) {
            // drain ONLY LDS (h writes), keep global loads in flight
            asm volatile("s_waitcnt lgkmcnt(0)" ::: "memory");
            __builtin_amdgcn_s_barrier();
            __builtin_amdgcn_sched_barrier(0);
        }
        cur = nxt;
    }
}

// ---------------------------------------------------------------------------
// k3 (r7 version): out = relu(y @ W_fc.T + b_fc). 128 blocks x 16 rows;
// 256 thr = 4 waves; A (y) cvt hi/lo per kt from LDS; B pre-split Wfc.
// ---------------------------------------------------------------------------
__global__ __launch_bounds__(256) void k3_out(
    const float* __restrict__ y,
    const short* __restrict__ Wfch, const short* __restrict__ Wfcl,
    const float* __restrict__ b_fc, float* __restrict__ out)
{
    __shared__ float ys[16][512];               // 32 KB
    const int tid  = threadIdx.x;
    const int w    = tid >> 6;
    const int lane = tid & 63;
    const int quad = lane >> 4;
    const int l15  = lane & 15;
    const int r0   = blockIdx.x * 16;

    #pragma unroll
    for (int p = 0; p < 8; ++p) {
        const int idx = p * 256 + tid;
        const int row = idx >> 7, c4 = idx & 127;
        *(f32x4*)&ys[row][c4 * 4] =
            *(const f32x4*)&y[(size_t)(r0 + row) * (2 * kH) + c4 * 4];
    }
    __syncthreads();

    f32x4 acc[2];
    acc[0] = (f32x4){0.f, 0.f, 0.f, 0.f};
    acc[1] = (f32x4){0.f, 0.f, 0.f, 0.f};

    #pragma unroll
    for (int kt = 0; kt < 16; ++kt) {
        const f32x4 a0 = *(const f32x4*)&ys[l15][kt * 32 + quad * 8];
        const f32x4 a1 = *(const f32x4*)&ys[l15][kt * 32 + quad * 8 + 4];
        bf16x8 ah, al;
        cvt8(a0, a1, ah, al);
        #pragma unroll
        for (int tau = 0; tau < 2; ++tau) {
            const int ng = w * 2 + tau;
            const size_t off = (size_t)((ng * 16 + kt) * 64 + lane) * 8;
            const bf16x8 bh = *(const bf16x8*)(Wfch + off);
            const bf16x8 bl = *(const bf16x8*)(Wfcl + off);
            acc[tau] = __builtin_amdgcn_mfma_f32_16x16x32_bf16(ah, bh, acc[tau], 0, 0, 0);
            acc[tau] = __builtin_amdgcn_mfma_f32_16x16x32_bf16(ah, bl, acc[tau], 0, 0, 0);
            acc[tau] = __builtin_amdgcn_mfma_f32_16x16x32_bf16(al, bh, acc[tau], 0, 0, 0);
        }
    }

    #pragma unroll
    for (int tau = 0; tau < 2; ++tau) {
        const int dout = (w * 2 + tau) * 16 + l15;
        const float bias = b_fc[dout];
        #pragma unroll
        for (int r = 0; r < 4; ++r)
            out[(size_t)(r0 + quad * 4 + r) * kDOUT + dout] =
                fmaxf(acc[tau][r] + bias, 0.f);
    }
}

// ---------------------------------------------------------------------------
extern "C" void kernel_launch(void* const* d_in, const int* in_sizes, int n_in,
                              void* d_out, int out_size, void* d_ws, size_t ws_size,
                              hipStream_t stream) {
    const float* x      = (const float*)d_in[0];
    const float* mask   = (const float*)d_in[1];
    const float* W_ih_f = (const float*)d_in[2];
    const float* W_hh_f = (const float*)d_in[3];
    const float* b_f    = (const float*)d_in[4];
    const float* W_ih_r = (const float*)d_in[5];
    const float* W_hh_r = (const float*)d_in[6];
    const float* b_r    = (const float*)d_in[7];
    const float* W_fc   = (const float*)d_in[8];
    const float* b_fc   = (const float*)d_in[9];
    float* out = (float*)d_out;

    float* ws     = (float*)d_ws;
    float* mask_t = ws;                        // 65536 f
    float* xWP_f  = mask_t + 65536;            // 2097152 f
    float* xWP_r  = xWP_f + 2097152;           // 2097152 f
    float* yb     = xWP_r + 2097152;           // 1048576 f
    short* Wp_f   = (short*)(yb + 1048576);    // 262144 bf16
    short* Wp_r   = Wp_f + 262144;             // 262144 bf16
    short* Wihh_f = Wp_r + 262144;             // 131072 bf16
    short* Wihl_f = Wihh_f + 131072;           // 131072 bf16
    short* Wihh_r = Wihl_f + 131072;           // 131072 bf16
    short* Wihl_r = Wihh_r + 131072;           // 131072 bf16
    short* Wfch   = Wihl_r + 131072;           // 65536 bf16
    short* Wfcl   = Wfch + 65536;              // 65536 bf16

    prep_k<<<128, 256, 0, stream>>>(
        W_ih_f, W_ih_r, Wihh_f, Wihl_f, Wihh_r, Wihl_r);

    k1_front<<<400, 256, 0, stream>>>(
        x, Wihh_f, Wihl_f, Wihh_r, Wihl_r,
        W_hh_f, W_hh_r, W_fc, mask,
        xWP_f, xWP_r, Wp_f, Wp_r, Wfch, Wfcl, mask_t);

    k2_lstm<<<256, 512, 0, stream>>>(mask_t, xWP_f, xWP_r, Wp_f, Wp_r,
                                     b_f, b_r, yb);
    k3_out<<<128, 256, 0, stream>>>(yb, Wfch, Wfcl, b_fc, out);
}

// Round 13
// 188.523 us; speedup vs baseline: 1.0361x; 1.0361x over previous
//
#include <hip/hip_runtime.h>
#include <math.h>

// Problem constants
constexpr int kB    = 64;
constexpr int kN    = 32;
constexpr int kDIN  = 128;
constexpr int kH    = 256;
constexpr int kG4   = 1024;   // 4*H
constexpr int kDOUT = 128;
constexpr int kBN   = 2048;   // B*N

typedef __attribute__((ext_vector_type(8))) short bf16x8;
typedef __attribute__((ext_vector_type(4))) float f32x4;

// fast sigmoid/tanh: v_exp_f32 + v_rcp_f32 (1-2 ulp, far below bf16-h noise)
__device__ __forceinline__ float sigm(float x) {
    return __builtin_amdgcn_rcpf(1.0f + __expf(-x));
}
__device__ __forceinline__ float tanh_f(float x) {
    return 1.0f - 2.0f * __builtin_amdgcn_rcpf(1.0f + __expf(2.0f * x));
}

// fp32 -> bf16 bits, round-to-nearest-even
__device__ __forceinline__ short f2bf(float f) {
    union { float f; unsigned u; } v; v.f = f;
    unsigned r = v.u + 0x7fffu + ((v.u >> 16) & 1u);
    return (short)(r >> 16);
}
__device__ __forceinline__ float bf2f(short h) {
    union { unsigned u; float f; } v; v.u = ((unsigned)(unsigned short)h) << 16;
    return v.f;
}
// fp32 -> (hi, lo) bf16 pair: hi + lo ~ f with ~2^-17 relative error
__device__ __forceinline__ void split_bf(float f, short& hi, short& lo) {
    const short h = f2bf(f);
    hi = h;
    lo = f2bf(f - bf2f(h));
}
// two f32x4 -> hi/lo bf16x8 fragments
__device__ __forceinline__ void cvt8(const f32x4 a, const f32x4 b,
                                     bf16x8& hi, bf16x8& lo) {
    #pragma unroll
    for (int j = 0; j < 4; ++j) { short h, l; split_bf(a[j], h, l); hi[j] = h; lo[j] = l; }
    #pragma unroll
    for (int j = 0; j < 4; ++j) { short h, l; split_bf(b[j], h, l); hi[4 + j] = h; lo[4 + j] = l; }
}

// ---------------------------------------------------------------------------
// k1_front (400 blocks x 256 thr), fused — ROUND-13: prep launch DELETED.
// GEMM blocks are now self-sufficient: B operand (W_ih) loaded directly from
// the original fp32 layout and hi/lo-converted in-kernel (the 64-gate slice
// per block is 32 KB, L2-resident after first touch). One fewer kernel +
// launch gap on the critical path.
//   [0,256)   xW GEMM (LDS x stage, per-kt A cvt, direct fp32 B + cvt)
//   [256,384) W_hh bf16 fragment pack (for k2)
//   [384,392) W_fc hi/lo pack (for k3)
//   [392,400) mask transpose -> mask_t [n][t][b] (for k2)
// ---------------------------------------------------------------------------
__global__ __launch_bounds__(256)
__attribute__((amdgpu_waves_per_eu(2, 2))) void k1_front(
    const float* __restrict__ x,
    const float* __restrict__ Wihf, const float* __restrict__ Wihr,
    const float* __restrict__ Whhf, const float* __restrict__ Whhr,
    const float* __restrict__ Wfc,  const float* __restrict__ mask,
    float* __restrict__ xWP_f, float* __restrict__ xWP_r,
    short* __restrict__ Wp_f,  short* __restrict__ Wp_r,
    short* __restrict__ Wfch,  short* __restrict__ Wfcl,
    float* __restrict__ mask_t)
{
    __shared__ float xs[64][128];               // 32 KB (GEMM blocks only)
    const int bx  = blockIdx.x;
    const int tid = threadIdx.x;

    if (bx >= 392) {                       // mask transpose
        const int base = (bx - 392) * 8192 + tid;
        #pragma unroll
        for (int i = 0; i < 32; ++i) {
            const int idx = base + i * 256;
            const int n = idx >> 11, tt = (idx >> 6) & 31, b = idx & 63;
            mask_t[idx] = mask[(size_t)b * 1024 + n * 32 + tt];
        }
        return;
    }
    if (bx >= 384) {                       // W_fc hi/lo pack
        const int ng   = bx - 384;         // 0..7
        const int lane = tid & 63;
        const int qd   = lane >> 4, l = lane & 15;
        #pragma unroll
        for (int p = 0; p < 4; ++p) {
            const int kt = p * 4 + (tid >> 6);
            const int ks = kt * 32 + qd * 8;
            bf16x8 vh, vl;
            #pragma unroll
            for (int j = 0; j < 8; ++j) {
                short h, lo;
                split_bf(Wfc[(size_t)(ng * 16 + l) * (2 * kH) + ks + j], h, lo);
                vh[j] = h; vl[j] = lo;
            }
            const size_t off = (size_t)((ng * 16 + kt) * 64 + lane) * 8;
            *(bf16x8*)(Wfch + off) = vh;
            *(bf16x8*)(Wfcl + off) = vl;
        }
        return;
    }
    if (bx >= 256) {                       // W_hh fragment pack (bf16, k2)
        const int idx = bx - 256;
        const int dir = idx >> 6;
        const int wv  = (idx >> 3) & 7;
        const int kt  = idx & 7;
        const float* src = dir ? Whhr : Whhf;
        short* dst = (dir ? Wp_r : Wp_f) + (size_t)((wv * 8 + kt) * 8) * 512;
        for (int i = tid; i < 512; i += 256) {
            const int tau = i >> 6, lane = i & 63;
            const int qd = lane >> 4, l = lane & 15;
            const int gate = (tau >> 1) * 256 + wv * 32 + (tau & 1) * 16 + l;
            const int ks = kt * 32 + qd * 8;
            bf16x8 v;
            #pragma unroll
            for (int j = 0; j < 8; ++j) v[j] = f2bf(src[(size_t)gate * kH + ks + j]);
            *(bf16x8*)(dst + tau * 512 + lane * 8) = v;
        }
        return;
    }

    // ---- xW GEMM blocks ----
    const int w    = tid >> 6;                  // wave 0..3
    const int lane = tid & 63;
    const int quad = lane >> 4;
    const int l15  = lane & 15;

    const int dir  = bx >> 7;
    const int rest = bx & 127;
    const int t    = rest >> 2;
    const int nt   = rest & 3;                  // 256-gate tile

    const float* __restrict__ Wih = dir ? Wihr : Wihf;
    float* __restrict__ xWP = dir ? xWP_r : xWP_f;

    #pragma unroll
    for (int p = 0; p < 8; ++p) {
        const int idx = p * 256 + tid;
        const int row = idx >> 5, c4 = idx & 31;
        *(f32x4*)&xs[row][c4 * 4] =
            *(const f32x4*)&x[((size_t)row * 32 + t) * kDIN + c4 * 4];
    }
    __syncthreads();

    f32x4 acc[4][4];                            // [tau][Mt]
    #pragma unroll
    for (int tau = 0; tau < 4; ++tau)
        #pragma unroll
        for (int Mt = 0; Mt < 4; ++Mt) acc[tau][Mt] = (f32x4){0.f, 0.f, 0.f, 0.f};

    #pragma unroll
    for (int kt = 0; kt < 4; ++kt) {
        bf16x8 ah[4], al[4];                    // per-kt A cvt: low residency
        #pragma unroll
        for (int Mt = 0; Mt < 4; ++Mt) {
            const f32x4 a0 = *(const f32x4*)&xs[Mt * 16 + l15][kt * 32 + quad * 8];
            const f32x4 a1 = *(const f32x4*)&xs[Mt * 16 + l15][kt * 32 + quad * 8 + 4];
            cvt8(a0, a1, ah[Mt], al[Mt]);
        }
        bf16x8 bh[4], bl[4];                    // direct fp32 W_ih + cvt
        #pragma unroll
        for (int tau = 0; tau < 4; ++tau) {
            const int g16 = nt * 16 + w * 4 + tau;
            const float* wrow = Wih + (size_t)(g16 * 16 + l15) * kDIN
                              + kt * 32 + quad * 8;
            const f32x4 b0 = *(const f32x4*)(wrow);
            const f32x4 b1 = *(const f32x4*)(wrow + 4);
            cvt8(b0, b1, bh[tau], bl[tau]);
        }
        #pragma unroll
        for (int tau = 0; tau < 4; ++tau)
            #pragma unroll
            for (int Mt = 0; Mt < 4; ++Mt) {
                acc[tau][Mt] = __builtin_amdgcn_mfma_f32_16x16x32_bf16(
                    ah[Mt], bh[tau], acc[tau][Mt], 0, 0, 0);
                acc[tau][Mt] = __builtin_amdgcn_mfma_f32_16x16x32_bf16(
                    ah[Mt], bl[tau], acc[tau][Mt], 0, 0, 0);
                acc[tau][Mt] = __builtin_amdgcn_mfma_f32_16x16x32_bf16(
                    al[Mt], bh[tau], acc[tau][Mt], 0, 0, 0);
            }
    }

    #pragma unroll
    for (int tau = 0; tau < 4; ++tau) {
        const int g16  = nt * 16 + w * 4 + tau;
        const int wg   = (g16 >> 1) & 7;
        const int taug = (g16 >> 4) * 2 + (g16 & 1);
        #pragma unroll
        for (int Mt = 0; Mt < 4; ++Mt)
            ((f32x4*)xWP)[(size_t)(t * 4 + Mt) * 4096 + wg * 512 + taug * 64
                          + quad * 16 + l15] = acc[tau][Mt];
    }
}

// ---------------------------------------------------------------------------
// k2: bidirectional LSTM recurrence (EXACT r10 config — measured 104.2 us;
// the proven local optimum: 16 waves / 128 regs / 4-2-2 tiers / __syncthreads.
// Every neighbor measured and lost: M=32 (r3), 5-2-1@8w (r8 spill),
// raw-barrier (r11 null), 4-2-2@8w (r12 -8%).)
// ---------------------------------------------------------------------------
__global__ __launch_bounds__(1024)
__attribute__((amdgpu_waves_per_eu(4, 4))) void k2_lstm(
    const float* __restrict__ mask_t,
    const float* __restrict__ xWP_f, const float* __restrict__ xWP_r,
    const short* __restrict__ Wp_f, const short* __restrict__ Wp_r,
    const float* __restrict__ b_f,  const float* __restrict__ b_r,
    float* __restrict__ y)
{
    constexpr int HP = 272;
    __shared__ short h_lds[2][16][HP];          // 17408 B
    __shared__ short w_lds[16][8][512];         // 131072 B: kt=4,5 x 4g per wave

    const int tid  = threadIdx.x;
    const int w    = tid >> 6;                  // 0..15
    const int lane = tid & 63;
    const int quad = lane >> 4;
    const int l15  = lane & 15;

    const int bx    = blockIdx.x;
    const int dir   = bx >> 7;                  // 0 fwd, 1 rev
    const int rest  = bx & 127;
    const int n_seq = rest >> 2;                // 0..31
    const int bq    = rest & 3;                 // batch quarter (16 each)

    const float* __restrict__ xWP = dir ? xWP_r : xWP_f;
    const short* __restrict__ Wp  = dir ? Wp_r  : Wp_f;
    const float* __restrict__ bb  = dir ? b_r   : b_f;

    const int wv = w >> 1;
    const int wo = w & 1;

    float bias[4];
    #pragma unroll
    for (int g = 0; g < 4; ++g)
        bias[g] = bb[g * 256 + w * 16 + l15];

    // tier 1: persist kt = 0..3 in registers
    bf16x8 wreg[4][4];
    #pragma unroll
    for (int kt = 0; kt < 4; ++kt)
        #pragma unroll
        for (int g = 0; g < 4; ++g)
            wreg[kt][g] = *(const bf16x8*)(
                Wp + (size_t)((wv * 8 + kt) * 8 + g * 2 + wo) * 512 + lane * 8);

    // tier 2: park kt = 4..5 in this wave's private LDS stash.
    #pragma unroll
    for (int f = 0; f < 8; ++f) {
        const int kt = 4 + (f >> 2), g = f & 3;
        *(bf16x8*)&w_lds[w][f][lane * 8] = *(const bf16x8*)(
            Wp + (size_t)((wv * 8 + kt) * 8 + g * 2 + wo) * 512 + lane * 8);
    }

    float c[4];
    #pragma unroll
    for (int i = 0; i < 4; ++i) c[i] = 0.f;

    const int nsteps = dir ? (kN - n_seq) : (n_seq + 1);
    const int t0     = dir ? (kN - 1) : 0;

    const f32x4* xWPv = (const f32x4*)xWP + (wv * 512 + wo * 64 + lane);

    f32x4 xwn[4];
    f32x4 mkn;
    {
        const f32x4* xb4 = xWPv + (size_t)(t0 * 4 + bq) * 4096;
        #pragma unroll
        for (int g = 0; g < 4; ++g) xwn[g] = xb4[g * 128];
        mkn = ((const f32x4*)mask_t)[(n_seq * 32 + t0) * 16 + bq * 4 + quad];
    }

    int zro = 0;                  // opaque 0: blocks LICM of tier-2/3 loads

    int cur = 0;
    for (int it = 0; it < nsteps; ++it) {
        const int t = dir ? (kN - 1 - it) : it;

        asm volatile("" : "+v"(zro));   // redefine each step -> loop-variant

        f32x4 acc[4];
        #pragma unroll
        for (int g = 0; g < 4; ++g)
            #pragma unroll
            for (int r = 0; r < 4; ++r)
                acc[g][r] = fmaf(mkn[r], xwn[g][r], bias[g]);

        {
            const int tn = (it + 1 < nsteps) ? (dir ? t - 1 : t + 1) : t;
            const f32x4* xb4 = xWPv + (size_t)(tn * 4 + bq) * 4096;
            #pragma unroll
            for (int g = 0; g < 4; ++g) xwn[g] = xb4[g * 128];
            mkn = ((const f32x4*)mask_t)[(n_seq * 32 + tn) * 16 + bq * 4 + quad];
        }

        if (it > 0) {
            #pragma unroll
            for (int kt = 0; kt < 4; ++kt) {
                const bf16x8 a = *(const bf16x8*)&h_lds[cur][l15][kt * 32 + quad * 8];
                #pragma unroll
                for (int g = 0; g < 4; ++g)
                    acc[g] = __builtin_amdgcn_mfma_f32_16x16x32_bf16(
                        a, wreg[kt][g], acc[g], 0, 0, 0);
            }
            #pragma unroll
            for (int kk = 0; kk < 2; ++kk) {
                const int kt = 4 + kk;
                const bf16x8 a = *(const bf16x8*)&h_lds[cur][l15][kt * 32 + quad * 8];
                #pragma unroll
                for (int g = 0; g < 4; ++g) {
                    const bf16x8 wf = *(const bf16x8*)&w_lds[w][kk * 4 + g][lane * 8 + zro];
                    acc[g] = __builtin_amdgcn_mfma_f32_16x16x32_bf16(
                        a, wf, acc[g], 0, 0, 0);
                }
            }
            #pragma unroll
            for (int kk = 0; kk < 2; ++kk) {
                const int kt = 6 + kk;
                const bf16x8 a = *(const bf16x8*)&h_lds[cur][l15][kt * 32 + quad * 8];
                #pragma unroll
                for (int g = 0; g < 4; ++g) {
                    const bf16x8 wf = *(const bf16x8*)(
                        Wp + (size_t)((wv * 8 + kt) * 8 + g * 2 + wo) * 512
                           + lane * 8 + zro);
                    acc[g] = __builtin_amdgcn_mfma_f32_16x16x32_bf16(
                        a, wf, acc[g], 0, 0, 0);
                }
            }
        }

        const int nxt = cur ^ 1;
        const int u = w * 16 + l15;
        #pragma unroll
        for (int r = 0; r < 4; ++r) {
            const float gI = acc[0][r];
            const float gF = acc[1][r];
            const float gG = acc[2][r];
            const float gO = acc[3][r];
            const float ct = sigm(gF) * c[r] + sigm(gI) * tanh_f(gG);
            c[r] = ct;
            const float hn = sigm(gO) * tanh_f(ct);
            const int m = quad * 4 + r;
            h_lds[nxt][m][u] = f2bf(hn);
            if (it == nsteps - 1)
                y[((size_t)(bq * 16 + m) * kN + n_seq) * (2 * kH)
                  + dir * kH + u] = hn;
        }
        if (it + 1 < nsteps) __syncthreads();
        cur = nxt;
    }
}

// ---------------------------------------------------------------------------
// k3 (r7 version): out = relu(y @ W_fc.T + b_fc). 128 blocks x 16 rows;
// 256 thr = 4 waves; A (y) cvt hi/lo per kt from LDS; B pre-split Wfc.
// ---------------------------------------------------------------------------
__global__ __launch_bounds__(256) void k3_out(
    const float* __restrict__ y,
    const short* __restrict__ Wfch, const short* __restrict__ Wfcl,
    const float* __restrict__ b_fc, float* __restrict__ out)
{
    __shared__ float ys[16][512];               // 32 KB
    const int tid  = threadIdx.x;
    const int w    = tid >> 6;
    const int lane = tid & 63;
    const int quad = lane >> 4;
    const int l15  = lane & 15;
    const int r0   = blockIdx.x * 16;

    #pragma unroll
    for (int p = 0; p < 8; ++p) {
        const int idx = p * 256 + tid;
        const int row = idx >> 7, c4 = idx & 127;
        *(f32x4*)&ys[row][c4 * 4] =
            *(const f32x4*)&y[(size_t)(r0 + row) * (2 * kH) + c4 * 4];
    }
    __syncthreads();

    f32x4 acc[2];
    acc[0] = (f32x4){0.f, 0.f, 0.f, 0.f};
    acc[1] = (f32x4){0.f, 0.f, 0.f, 0.f};

    #pragma unroll
    for (int kt = 0; kt < 16; ++kt) {
        const f32x4 a0 = *(const f32x4*)&ys[l15][kt * 32 + quad * 8];
        const f32x4 a1 = *(const f32x4*)&ys[l15][kt * 32 + quad * 8 + 4];
        bf16x8 ah, al;
        cvt8(a0, a1, ah, al);
        #pragma unroll
        for (int tau = 0; tau < 2; ++tau) {
            const int ng = w * 2 + tau;
            const size_t off = (size_t)((ng * 16 + kt) * 64 + lane) * 8;
            const bf16x8 bh = *(const bf16x8*)(Wfch + off);
            const bf16x8 bl = *(const bf16x8*)(Wfcl + off);
            acc[tau] = __builtin_amdgcn_mfma_f32_16x16x32_bf16(ah, bh, acc[tau], 0, 0, 0);
            acc[tau] = __builtin_amdgcn_mfma_f32_16x16x32_bf16(ah, bl, acc[tau], 0, 0, 0);
            acc[tau] = __builtin_amdgcn_mfma_f32_16x16x32_bf16(al, bh, acc[tau], 0, 0, 0);
        }
    }

    #pragma unroll
    for (int tau = 0; tau < 2; ++tau) {
        const int dout = (w * 2 + tau) * 16 + l15;
        const float bias = b_fc[dout];
        #pragma unroll
        for (int r = 0; r < 4; ++r)
            out[(size_t)(r0 + quad * 4 + r) * kDOUT + dout] =
                fmaxf(acc[tau][r] + bias, 0.f);
    }
}

// ---------------------------------------------------------------------------
extern "C" void kernel_launch(void* const* d_in, const int* in_sizes, int n_in,
                              void* d_out, int out_size, void* d_ws, size_t ws_size,
                              hipStream_t stream) {
    const float* x      = (const float*)d_in[0];
    const float* mask   = (const float*)d_in[1];
    const float* W_ih_f = (const float*)d_in[2];
    const float* W_hh_f = (const float*)d_in[3];
    const float* b_f    = (const float*)d_in[4];
    const float* W_ih_r = (const float*)d_in[5];
    const float* W_hh_r = (const float*)d_in[6];
    const float* b_r    = (const float*)d_in[7];
    const float* W_fc   = (const float*)d_in[8];
    const float* b_fc   = (const float*)d_in[9];
    float* out = (float*)d_out;

    float* ws     = (float*)d_ws;
    float* mask_t = ws;                        // 65536 f
    float* xWP_f  = mask_t + 65536;            // 2097152 f
    float* xWP_r  = xWP_f + 2097152;           // 2097152 f
    float* yb     = xWP_r + 2097152;           // 1048576 f
    short* Wp_f   = (short*)(yb + 1048576);    // 262144 bf16
    short* Wp_r   = Wp_f + 262144;             // 262144 bf16
    short* Wfch   = Wp_r + 262144;             // 65536 bf16
    short* Wfcl   = Wfch + 65536;              // 65536 bf16

    k1_front<<<400, 256, 0, stream>>>(
        x, W_ih_f, W_ih_r, W_hh_f, W_hh_r, W_fc, mask,
        xWP_f, xWP_r, Wp_f, Wp_r, Wfch, Wfcl, mask_t);

    k2_lstm<<<256, 1024, 0, stream>>>(mask_t, xWP_f, xWP_r, Wp_f, Wp_r,
                                      b_f, b_r, yb);
    k3_out<<<128, 256, 0, stream>>>(yb, Wfch, Wfcl, b_fc, out);
}